// Round 1
// baseline (178.211 us; speedup 1.0000x reference)
//
#include <hip/hip_runtime.h>
#include <hip/hip_bf16.h>
#include <math.h>

// Problem constants (SchNet reference)
#define NATOMS 16384
#define NMOL   512
#define APM    32
#define GDIM   50
#define KTAB   4096   // filter lookup-table knots over d in [0,6] (nearest-knot)

#define STRH 132      // s_h row stride (floats), 528B
#define STRA 136      // s_agg / s_t row stride (ushorts), 272B

typedef __attribute__((ext_vector_type(8))) short   short8;   // 8 bf16 (A/B frag)
typedef __attribute__((ext_vector_type(4))) float   floatx4;  // C/D frag

// fast shifted softplus: log(1+exp(x)) - log2, via HW v_exp_f32/v_log_f32
__device__ __forceinline__ float ssp(float x) {
    float e = __expf(-fabsf(x));
    return fmaxf(x, 0.0f) + __logf(1.0f + e) - 0.69314718055994531f;
}

__device__ __forceinline__ unsigned short f2bf(float x) {
    union { float f; unsigned int u; } v; v.f = x;
    unsigned int lsb = (v.u >> 16) & 1u;
    v.u += 0x7fffu + lsb;
    return (unsigned short)(v.u >> 16);
}

__device__ __forceinline__ unsigned int pk2bf(float a, float b) {
    __hip_bfloat162 h = __float22bfloat162_rn(make_float2(a, b));
    unsigned int u;
    __builtin_memcpy(&u, &h, 4);
    return u;
}

// ---------------------------------------------------------------------------
// MEGA-SETUP (single dispatch, 3 block regions):
//  [0,EB):        per-edge meta {knot<<10 | src<<5 | dst} (nearest knot) + rowptr
//  [EB,EB+WB):    weights fp32 -> bf16 B-frag transpose (9x128x128 + out1 64x128)
//  [EB+WB, +192): filter table, 64 tiles x 3 layers, plain bf16 rows:
//                 T[l][k][f] = ((ssp(ea(d_k)@w1+b1)@w2)+b2)*cut(d_k)
// ---------------------------------------------------------------------------
#define KW1 72
#define KW2 136
#define NTILE (KTAB / 64)   // 64 tiles per layer

__global__ __launch_bounds__(256) void mega_setup_kernel(
    const float* __restrict__ pos, const int* __restrict__ eidx, int E, int EB,
    int* __restrict__ rowptr,
    const float* __restrict__ cf1, const float* __restrict__ cf2,
    const float* __restrict__ lin, const float* __restrict__ out1,
    unsigned short* __restrict__ Wtall, unsigned int* __restrict__ meta,
    const float* __restrict__ w1_, const float* __restrict__ b1_,
    const float* __restrict__ w2_, const float* __restrict__ b2_,
    unsigned short* __restrict__ Tt)
{
    const int WB = (9 * 16384 + 64 * 128 + 255) / 256;
    const int b = blockIdx.x;
    const int tid = threadIdx.x;

    if (b < EB) {
        int idx = b * 256 + tid;
        if (idx < E) {
            int s = eidx[idx], t = eidx[E + idx];
            float dx = pos[3 * s]     - pos[3 * t];
            float dy = pos[3 * s + 1] - pos[3 * t + 1];
            float dz = pos[3 * s + 2] - pos[3 * t + 2];
            float d  = sqrtf(dx * dx + dy * dy + dz * dz);
            float u  = d * (float)(KTAB - 1) / 6.0f;
            int i = min((int)(u + 0.5f), KTAB - 1);   // nearest knot
            meta[idx] = ((unsigned)i << 10) | ((unsigned)(s & 31) << 5) | (unsigned)(t & 31);
        } else if (idx < E + NATOMS + 1) {
            int a = idx - E;
            int lo = 0, hi = E;
            while (lo < hi) { int mid = (lo + hi) >> 1; if (eidx[mid] < a) lo = mid + 1; else hi = mid; }
            rowptr[a] = lo;
        }
        return;
    }
    if (b < EB + WB) {
        int idx = (b - EB) * 256 + tid;
        if (idx < 9 * 16384) {
            int wi = idx >> 14, rem = idx & 16383;
            int n = rem >> 7, k = rem & 127;
            int l = wi / 3, which = wi % 3;
            const float* src = (which == 0) ? cf1 : (which == 1) ? cf2 : lin;
            Wtall[idx] = f2bf(src[(size_t)l * 16384 + k * 128 + n]);
        } else if (idx < 9 * 16384 + 64 * 128) {
            int q = idx - 9 * 16384;
            int n = q >> 7, k = q & 127;
            Wtall[idx] = f2bf(out1[k * 64 + n]);
        }
        return;
    }

    // ---------------- table region: tt = (layer, tile) ----------------
    __shared__ unsigned short s_bufA[128 * KW2];   // w2T
    __shared__ unsigned short s_bufB[128 * KW1];   // w1T, then s_t (alias)

    const int tt = b - EB - WB;
    const int l  = tt / NTILE;
    const int bx = tt % NTILE;
    const float* w1 = w1_ + (size_t)l * GDIM * 128;
    const float* b1 = b1_ + (size_t)l * 128;
    const float* w2 = w2_ + (size_t)l * 128 * 128;
    const float* b2 = b2_ + (size_t)l * 128;
    unsigned short* Tg = Tt + (size_t)l * KTAB * 128;

    unsigned short* s_w1T = s_bufB;                // [128][KW1]
    unsigned short* s_w2T = s_bufA;                // [128][KW2]
    unsigned short* s_t   = s_bufB;                // [64][KW2] (after barrier)

    for (int i = tid; i < GDIM * 128; i += 256) {
        int g = i >> 7, f = i & 127;
        s_w1T[f * KW1 + g] = f2bf(w1[i]);
    }
    for (int i = tid; i < (64 - GDIM) * 128; i += 256) {
        int g = GDIM + (i >> 7), f = i & 127;
        s_w1T[f * KW1 + g] = 0;
    }
    for (int i = tid; i < 128 * 128; i += 256) {
        int k = i >> 7, n = i & 127;
        s_w2T[n * KW2 + k] = f2bf(w2[i]);
    }

    const int lane = tid & 63;
    const int w    = tid >> 6;
    const int l15  = lane & 15;
    const int quad = lane >> 4;

    float b1v[8], b2v[8];
    #pragma unroll
    for (int nt = 0; nt < 8; nt++) {
        b1v[nt] = b1[nt * 16 + l15];
        b2v[nt] = b2[nt * 16 + l15];
    }
    __syncthreads();

    const float hstep = 6.0f / (float)(KTAB - 1);
    const float step  = 6.0f / 49.0f;
    const float coeff = -0.5f / (step * step);
    const float pioc  = 3.14159265358979323846f / 6.0f;
    const int k0 = bx * 64;
    const float dm = (float)(k0 + w * 16 + l15) * hstep;

    floatx4 acc1[8];
    #pragma unroll
    for (int nt = 0; nt < 8; nt++) acc1[nt] = (floatx4){0.f, 0.f, 0.f, 0.f};
    #pragma unroll
    for (int ks = 0; ks < 2; ks++) {
        unsigned int ap[4];
        #pragma unroll
        for (int jj = 0; jj < 4; jj++) {
            int g0 = ks * 32 + quad * 8 + 2 * jj;
            float d0 = dm - (float)g0 * step;
            float d1 = dm - (float)(g0 + 1) * step;
            float v0 = (g0 < GDIM)     ? __expf(coeff * d0 * d0) : 0.0f;
            float v1 = (g0 + 1 < GDIM) ? __expf(coeff * d1 * d1) : 0.0f;
            ap[jj] = pk2bf(v0, v1);
        }
        short8 af;
        __builtin_memcpy(&af, ap, 16);
        #pragma unroll
        for (int nt = 0; nt < 8; nt++) {
            short8 bfg = *(const short8*)&s_w1T[(nt * 16 + l15) * KW1 + ks * 32 + quad * 8];
            acc1[nt] = __builtin_amdgcn_mfma_f32_16x16x32_bf16(af, bfg, acc1[nt], 0, 0, 0);
        }
    }
    __syncthreads();   // all waves done reading s_w1T; s_t may alias it

    #pragma unroll
    for (int nt = 0; nt < 8; nt++) {
        #pragma unroll
        for (int r = 0; r < 4; r++) {
            int row = w * 16 + quad * 4 + r;
            s_t[row * KW2 + nt * 16 + l15] = f2bf(ssp(acc1[nt][r] + b1v[nt]));
        }
    }
    // no barrier: wave reads only rows it wrote

    floatx4 acc2[8];
    #pragma unroll
    for (int nt = 0; nt < 8; nt++) acc2[nt] = (floatx4){0.f, 0.f, 0.f, 0.f};
    #pragma unroll
    for (int ks = 0; ks < 4; ks++) {
        short8 af = *(const short8*)&s_t[(w * 16 + l15) * KW2 + ks * 32 + quad * 8];
        #pragma unroll
        for (int nt = 0; nt < 8; nt++) {
            short8 bfg = *(const short8*)&s_w2T[(nt * 16 + l15) * KW2 + ks * 32 + quad * 8];
            acc2[nt] = __builtin_amdgcn_mfma_f32_16x16x32_bf16(af, bfg, acc2[nt], 0, 0, 0);
        }
    }

    #pragma unroll
    for (int nt = 0; nt < 8; nt++) {
        #pragma unroll
        for (int r = 0; r < 4; r++) {
            int row = w * 16 + quad * 4 + r;
            float d = (float)(k0 + row) * hstep;
            float cut = 0.5f * (__cosf(d * pioc) + 1.0f);
            Tg[(size_t)(k0 + row) * 128 + nt * 16 + l15] = f2bf((acc2[nt][r] + b2v[nt]) * cut);
        }
    }
}

// ---------------------------------------------------------------------------
// Fully-fused SchNet: one block = one molecule, 512 threads = 8 waves.
// GEMM tile per wave: rows (w&1)*16, cols (w>>1)*32.
// Gather (R9 rewrite): padded per-atom slot table (32 slots/atom, uint2 =
// precomputed {table byte off, hx byte off}, sentinel-padded to batch
// boundary -> no bounds check, no field extraction in the hot loop).
// 2 edges per wave-step: 32 lanes x 4 channels, dwordx2 table load (saddr,
// 32-bit offset), ds_read_b128 hx. ~6 VALU/edge vs ~18 in R8 shape.
// ---------------------------------------------------------------------------
__global__ __launch_bounds__(512, 4) void fused_schnet_kernel(
    const int* __restrict__ z, const float* __restrict__ emb,
    const int* __restrict__ rowptr, const unsigned int* __restrict__ meta,
    const unsigned short* __restrict__ Tt,
    const unsigned short* __restrict__ Wtall,
    const float* __restrict__ cf2_b, const float* __restrict__ lin_b,
    const float* __restrict__ out1_b, const float* __restrict__ out2_w,
    const float* __restrict__ out2_b,
    float* __restrict__ out)
{
    __shared__ float s_h[32 * STRH];                 // 16.9 KB fp32 node state
    __shared__ float s_hx[33 * 128];                 // 16.9 KB; row 32 = zeros
    __shared__ unsigned short s_agg[32 * STRA];      //  8.7 KB bf16
    __shared__ uint2 s_meta2[32 * 32];               //  8.0 KB padded slots
    __shared__ float s_red;
    unsigned short* s_t = (unsigned short*)s_hx;     // [32][STRA] alias (8.7KB)

    const int tid  = threadIdx.x;
    const int lane = tid & 63;
    const int w    = tid >> 6;          // wave 0..7
    const int l15  = lane & 15;
    const int quad = lane >> 4;
    const int r16  = (w & 1) * 16;      // GEMM row tile
    const int c32  = (w >> 1) * 32;     // GEMM col tile
    const int B0   = blockIdx.x * 32;   // molecule base atom

    const int half = lane >> 5;         // gather: which edge of the pair
    const int l31  = lane & 31;
    const unsigned tOff = (unsigned)(l31 << 3);   // 8B into table row (4 bf16)
    const unsigned hOff = (unsigned)(l31 << 4);   // 16B into hx row (4 f32)

    // init h; zero hx dummy row; sentinel-fill slot table
    for (int i = tid; i < 32 * 128; i += 512) {
        int row = i >> 7, col = i & 127;
        s_h[row * STRH + col] = emb[(size_t)z[B0 + row] * 128 + col];
    }
    if (tid < 128) s_hx[32 * 128 + tid] = 0.0f;
    if (tid == 0) s_red = 0.0f;
    for (int i = tid; i < 32 * 32; i += 512)
        s_meta2[i] = make_uint2(0u, 32u << 9);       // sentinel: hx row 32 (zeros)

    const int ebase = rowptr[B0];
    const int nE    = rowptr[B0 + 32] - ebase;

    __syncthreads();   // sentinel fill complete before slot overwrite

    // stage edge metadata into padded per-atom slots with precomputed byte offs
    for (int i = tid; i < nE; i += 512) {
        unsigned q = meta[ebase + i];
        int a = (int)((q >> 5) & 31u);
        int slot = i - (rowptr[B0 + a] - ebase);
        s_meta2[(a << 5) + slot] = make_uint2((q >> 10) << 8, (q & 31u) << 9);
    }

    // local row pointers for this wave's 4 atoms (5 bounds in lanes 0..4)
    const int rp = rowptr[B0 + w * 4 + min(lane, 4)] - ebase;

    const unsigned short* WtO = Wtall + 9 * 16384;   // out1^T
    const char* hxB = (const char*)s_hx;

    for (int l = 0; l < 3; l++) {
        const unsigned short* W1 = Wtall + (size_t)(l * 3 + 0) * 16384;
        const unsigned short* W2 = Wtall + (size_t)(l * 3 + 1) * 16384;
        const unsigned short* W3 = Wtall + (size_t)(l * 3 + 2) * 16384;
        const char* TlB = (const char*)(Tt + (size_t)l * KTAB * 128);

        __syncthreads();   // h ready (also covers init/meta staging at l=0)

        // ---- GEMM1: hx = h @ cf1 (16x32 tile per wave) ----
        floatx4 acc[2];
        #pragma unroll
        for (int nt = 0; nt < 2; nt++) acc[nt] = (floatx4){0.f, 0.f, 0.f, 0.f};
        #pragma unroll
        for (int ks = 0; ks < 4; ks++) {
            const float* hp = &s_h[(r16 + l15) * STRH + ks * 32 + quad * 8];
            float4 xa = *(const float4*)hp;
            float4 xb = *(const float4*)(hp + 4);
            unsigned int ap[4];
            ap[0] = pk2bf(xa.x, xa.y); ap[1] = pk2bf(xa.z, xa.w);
            ap[2] = pk2bf(xb.x, xb.y); ap[3] = pk2bf(xb.z, xb.w);
            short8 af;
            __builtin_memcpy(&af, ap, 16);
            #pragma unroll
            for (int nt = 0; nt < 2; nt++) {
                short8 bfg = *(const short8*)&W1[(size_t)(c32 + nt * 16 + l15) * 128 + ks * 32 + quad * 8];
                acc[nt] = __builtin_amdgcn_mfma_f32_16x16x32_bf16(af, bfg, acc[nt], 0, 0, 0);
            }
        }
        #pragma unroll
        for (int nt = 0; nt < 2; nt++) {
            #pragma unroll
            for (int r = 0; r < 4; r++)
                s_hx[(r16 + quad * 4 + r) * 128 + c32 + nt * 16 + l15] = acc[nt][r];
        }

        __syncthreads();   // hx complete before gather reads

        // ---- gather: wave per 4 atoms, 2 edges/step, 4 ch/lane ----
        for (int al = 0; al < 4; al++) {
            const int atom = w * 4 + al;
            const int deg  = __shfl(rp, al + 1) - __shfl(rp, al);
            const uint2* mp = &s_meta2[(atom << 5) + half];
            float pa[4][4];
            #pragma unroll
            for (int j = 0; j < 4; j++) {
                #pragma unroll
                for (int c = 0; c < 4; c++) pa[j][c] = 0.0f;
            }
            const int nb = (deg + 7) >> 3;   // batches of 8 edges (4 steps x 2)
            for (int bb = 0; bb < nb; bb++) {
                #pragma unroll
                for (int j = 0; j < 4; j++) {
                    uint2 m  = mp[(bb << 3) + (j << 1)];
                    uint2 tp = *(const uint2*)(TlB + (m.x + tOff));
                    float4 hv = *(const float4*)(hxB + (m.y + hOff));
                    pa[j][0] = fmaf(hv.x, __uint_as_float(tp.x << 16),         pa[j][0]);
                    pa[j][1] = fmaf(hv.y, __uint_as_float(tp.x & 0xffff0000u), pa[j][1]);
                    pa[j][2] = fmaf(hv.z, __uint_as_float(tp.y << 16),         pa[j][2]);
                    pa[j][3] = fmaf(hv.w, __uint_as_float(tp.y & 0xffff0000u), pa[j][3]);
                }
            }
            float c0 = (pa[0][0] + pa[1][0]) + (pa[2][0] + pa[3][0]);
            float c1 = (pa[0][1] + pa[1][1]) + (pa[2][1] + pa[3][1]);
            float c2 = (pa[0][2] + pa[1][2]) + (pa[2][2] + pa[3][2]);
            float c3 = (pa[0][3] + pa[1][3]) + (pa[2][3] + pa[3][3]);
            c0 += __shfl_xor(c0, 32);
            c1 += __shfl_xor(c1, 32);
            c2 += __shfl_xor(c2, 32);
            c3 += __shfl_xor(c3, 32);
            if (half == 0) {
                uint2 pk = make_uint2(pk2bf(c0, c1), pk2bf(c2, c3));
                *(uint2*)&s_agg[atom * STRA + (l31 << 2)] = pk;
            }
        }

        __syncthreads();   // agg complete; hx reads done (s_t alias safe)

        // ---- GEMM2: t = ssp(agg @ cf2 + b) ----
        float bva[2], bvb[2];
        #pragma unroll
        for (int nt = 0; nt < 2; nt++) {
            bva[nt] = cf2_b[l * 128 + c32 + nt * 16 + l15];
            bvb[nt] = lin_b[l * 128 + c32 + nt * 16 + l15];
        }
        #pragma unroll
        for (int nt = 0; nt < 2; nt++) acc[nt] = (floatx4){0.f, 0.f, 0.f, 0.f};
        #pragma unroll
        for (int ks = 0; ks < 4; ks++) {
            short8 af = *(const short8*)&s_agg[(r16 + l15) * STRA + ks * 32 + quad * 8];
            #pragma unroll
            for (int nt = 0; nt < 2; nt++) {
                short8 bfg = *(const short8*)&W2[(size_t)(c32 + nt * 16 + l15) * 128 + ks * 32 + quad * 8];
                acc[nt] = __builtin_amdgcn_mfma_f32_16x16x32_bf16(af, bfg, acc[nt], 0, 0, 0);
            }
        }
        #pragma unroll
        for (int nt = 0; nt < 2; nt++) {
            #pragma unroll
            for (int r = 0; r < 4; r++) {
                int row = r16 + quad * 4 + r;
                s_t[row * STRA + c32 + nt * 16 + l15] = f2bf(ssp(acc[nt][r] + bva[nt]));
            }
        }

        __syncthreads();   // t complete (cross-wave cols needed by GEMM3)

        // ---- GEMM3: h += t @ lin + b ----
        #pragma unroll
        for (int nt = 0; nt < 2; nt++) acc[nt] = (floatx4){0.f, 0.f, 0.f, 0.f};
        #pragma unroll
        for (int ks = 0; ks < 4; ks++) {
            short8 af = *(const short8*)&s_t[(r16 + l15) * STRA + ks * 32 + quad * 8];
            #pragma unroll
            for (int nt = 0; nt < 2; nt++) {
                short8 bfg = *(const short8*)&W3[(size_t)(c32 + nt * 16 + l15) * 128 + ks * 32 + quad * 8];
                acc[nt] = __builtin_amdgcn_mfma_f32_16x16x32_bf16(af, bfg, acc[nt], 0, 0, 0);
            }
        }
        #pragma unroll
        for (int nt = 0; nt < 2; nt++) {
            #pragma unroll
            for (int r = 0; r < 4; r++) {
                int row = r16 + quad * 4 + r;
                s_h[row * STRH + c32 + nt * 16 + l15] += acc[nt][r] + bvb[nt];
            }
        }
        // loop-top __syncthreads covers h
    }

    __syncthreads();

    // ---- head: out = sum_a ssp(h@out1 + b1)@out2 + 32*b2 ----
    const int c16 = (w >> 1) * 16;   // out1: 64 cols = 4 col tiles x 2 row tiles
    floatx4 ha = (floatx4){0.f, 0.f, 0.f, 0.f};
    #pragma unroll
    for (int ks = 0; ks < 4; ks++) {
        const float* hp = &s_h[(r16 + l15) * STRH + ks * 32 + quad * 8];
        float4 xa = *(const float4*)hp;
        float4 xb = *(const float4*)(hp + 4);
        unsigned int ap[4];
        ap[0] = pk2bf(xa.x, xa.y); ap[1] = pk2bf(xa.z, xa.w);
        ap[2] = pk2bf(xb.x, xb.y); ap[3] = pk2bf(xb.z, xb.w);
        short8 af;
        __builtin_memcpy(&af, ap, 16);
        short8 bfg = *(const short8*)&WtO[(size_t)(c16 + l15) * 128 + ks * 32 + quad * 8];
        ha = __builtin_amdgcn_mfma_f32_16x16x32_bf16(af, bfg, ha, 0, 0, 0);
    }
    float part = 0.0f;
    {
        float b1o = out1_b[c16 + l15];
        float o2  = out2_w[c16 + l15];
        #pragma unroll
        for (int r = 0; r < 4; r++)
            part += ssp(ha[r] + b1o) * o2;
    }
    #pragma unroll
    for (int off = 32; off > 0; off >>= 1) part += __shfl_down(part, off);
    if (lane == 0) atomicAdd(&s_red, part);
    __syncthreads();
    if (tid == 0) out[blockIdx.x] = s_red + 32.0f * out2_b[0];
}

extern "C" void kernel_launch(void* const* d_in, const int* in_sizes, int n_in,
                              void* d_out, int out_size, void* d_ws, size_t ws_size,
                              hipStream_t stream)
{
    const int*   z      = (const int*)d_in[0];
    const float* pos    = (const float*)d_in[1];
    const int*   eidx   = (const int*)d_in[3];
    const float* emb    = (const float*)d_in[4];
    const float* mlp_w1 = (const float*)d_in[5];
    const float* mlp_b1 = (const float*)d_in[6];
    const float* mlp_w2 = (const float*)d_in[7];
    const float* mlp_b2 = (const float*)d_in[8];
    const float* cf1_w  = (const float*)d_in[9];
    const float* cf2_w  = (const float*)d_in[10];
    const float* cf2_b  = (const float*)d_in[11];
    const float* lin_w  = (const float*)d_in[12];
    const float* lin_b  = (const float*)d_in[13];
    const float* out1_w = (const float*)d_in[14];
    const float* out1_b = (const float*)d_in[15];
    const float* out2_w = (const float*)d_in[16];
    const float* out2_b = (const float*)d_in[17];
    const int E = in_sizes[3] / 2;

    // workspace carve-up (16B-aligned sections)
    char* p = (char*)d_ws;
    unsigned int* meta = (unsigned int*)p;        p += ((size_t)(E + 1) * 4 + 63) & ~63ULL;
    unsigned short* Tt = (unsigned short*)p;      p += (size_t)3 * KTAB * 128 * 2;
    int* rowptr = (int*)p;                        p += ((size_t)(NATOMS + 1) * 4 + 63) & ~63ULL;
    unsigned short* Wtall = (unsigned short*)p;   // 9*16384 + 64*128 ushorts

    const int EB = (E + NATOMS + 1 + 255) / 256;
    const int WB = (9 * 16384 + 64 * 128 + 255) / 256;
    const int TB = NTILE * 3;
    mega_setup_kernel<<<EB + WB + TB, 256, 0, stream>>>(
        pos, eidx, E, EB, rowptr, cf1_w, cf2_w, lin_w, out1_w, Wtall, meta,
        mlp_w1, mlp_b1, mlp_w2, mlp_b2, Tt);

    fused_schnet_kernel<<<NMOL, 512, 0, stream>>>(
        z, emb, rowptr, meta, Tt, Wtall,
        cf2_b, lin_b, out1_b, out2_w, out2_b, (float*)d_out);
}

// Round 2
// 169.950 us; speedup vs baseline: 1.0486x; 1.0486x over previous
//
#include <hip/hip_runtime.h>
#include <hip/hip_bf16.h>
#include <math.h>

// Problem constants (SchNet reference)
#define NATOMS 16384
#define NMOL   512
#define APM    32
#define GDIM   50
#define KTAB   4096   // filter lookup-table knots over d in [0,6] (nearest-knot)

#define STRH 132      // s_h row stride (floats), 528B
#define STRA 136      // s_agg / s_t row stride (ushorts), 272B

typedef __attribute__((ext_vector_type(8))) short   short8;   // 8 bf16 (A/B frag)
typedef __attribute__((ext_vector_type(4))) float   floatx4;  // C/D frag

// fast shifted softplus: log(1+exp(x)) - log2, via HW v_exp_f32/v_log_f32
__device__ __forceinline__ float ssp(float x) {
    float e = __expf(-fabsf(x));
    return fmaxf(x, 0.0f) + __logf(1.0f + e) - 0.69314718055994531f;
}

__device__ __forceinline__ unsigned short f2bf(float x) {
    union { float f; unsigned int u; } v; v.f = x;
    unsigned int lsb = (v.u >> 16) & 1u;
    v.u += 0x7fffu + lsb;
    return (unsigned short)(v.u >> 16);
}

__device__ __forceinline__ unsigned int pk2bf(float a, float b) {
    __hip_bfloat162 h = __float22bfloat162_rn(make_float2(a, b));
    unsigned int u;
    __builtin_memcpy(&u, &h, 4);
    return u;
}

// ---------------------------------------------------------------------------
// MEGA-SETUP (single dispatch, 3 block regions):
//  [0,EB):        per-edge meta {knot<<10 | src<<5 | dst} + rowptr + zero-rows
//  [EB,EB+WB):    weights fp32 -> bf16 B-frag transpose (9x128x128 + out1 64x128)
//  [EB+WB, +192): filter table, 64 tiles x 3 layers, plain bf16 rows:
//                 T[l][k][f] = ((ssp(ea(d_k)@w1+b1)@w2)+b2)*cut(d_k)
//  Each layer gets KTAB+1 rows; row KTAB is all-zero (dense-gather sentinel).
// ---------------------------------------------------------------------------
#define KW1 72
#define KW2 136
#define NTILE (KTAB / 64)   // 64 tiles per layer

__global__ __launch_bounds__(256) void mega_setup_kernel(
    const float* __restrict__ pos, const int* __restrict__ eidx, int E, int EB,
    int* __restrict__ rowptr,
    const float* __restrict__ cf1, const float* __restrict__ cf2,
    const float* __restrict__ lin, const float* __restrict__ out1,
    unsigned short* __restrict__ Wtall, unsigned int* __restrict__ meta,
    const float* __restrict__ w1_, const float* __restrict__ b1_,
    const float* __restrict__ w2_, const float* __restrict__ b2_,
    unsigned short* __restrict__ Tt)
{
    const int WB = (9 * 16384 + 64 * 128 + 255) / 256;
    const int b = blockIdx.x;
    const int tid = threadIdx.x;

    if (b < EB) {
        int idx = b * 256 + tid;
        if (idx < E) {
            int s = eidx[idx], t = eidx[E + idx];
            float dx = pos[3 * s]     - pos[3 * t];
            float dy = pos[3 * s + 1] - pos[3 * t + 1];
            float dz = pos[3 * s + 2] - pos[3 * t + 2];
            float d  = sqrtf(dx * dx + dy * dy + dz * dz);
            float u  = d * (float)(KTAB - 1) / 6.0f;
            int i = min((int)(u + 0.5f), KTAB - 1);   // nearest knot
            meta[idx] = ((unsigned)i << 10) | ((unsigned)(s & 31) << 5) | (unsigned)(t & 31);
        } else if (idx < E + NATOMS + 1) {
            int a = idx - E;
            int lo = 0, hi = E;
            while (lo < hi) { int mid = (lo + hi) >> 1; if (eidx[mid] < a) lo = mid + 1; else hi = mid; }
            rowptr[a] = lo;
        } else if (idx < E + NATOMS + 1 + 3 * 128) {
            int q = idx - (E + NATOMS + 1);
            int l = q >> 7, f = q & 127;
            Tt[(size_t)l * (KTAB + 1) * 128 + (size_t)KTAB * 128 + f] = 0;  // zero row
        }
        return;
    }
    if (b < EB + WB) {
        int idx = (b - EB) * 256 + tid;
        if (idx < 9 * 16384) {
            int wi = idx >> 14, rem = idx & 16383;
            int n = rem >> 7, k = rem & 127;
            int l = wi / 3, which = wi % 3;
            const float* src = (which == 0) ? cf1 : (which == 1) ? cf2 : lin;
            Wtall[idx] = f2bf(src[(size_t)l * 16384 + k * 128 + n]);
        } else if (idx < 9 * 16384 + 64 * 128) {
            int q = idx - 9 * 16384;
            int n = q >> 7, k = q & 127;
            Wtall[idx] = f2bf(out1[k * 64 + n]);
        }
        return;
    }

    // ---------------- table region: tt = (layer, tile) ----------------
    __shared__ unsigned short s_bufA[128 * KW2];   // w2T
    __shared__ unsigned short s_bufB[128 * KW1];   // w1T, then s_t (alias)

    const int tt = b - EB - WB;
    const int l  = tt / NTILE;
    const int bx = tt % NTILE;
    const float* w1 = w1_ + (size_t)l * GDIM * 128;
    const float* b1 = b1_ + (size_t)l * 128;
    const float* w2 = w2_ + (size_t)l * 128 * 128;
    const float* b2 = b2_ + (size_t)l * 128;
    unsigned short* Tg = Tt + (size_t)l * (KTAB + 1) * 128;

    unsigned short* s_w1T = s_bufB;                // [128][KW1]
    unsigned short* s_w2T = s_bufA;                // [128][KW2]
    unsigned short* s_t   = s_bufB;                // [64][KW2] (after barrier)

    for (int i = tid; i < GDIM * 128; i += 256) {
        int g = i >> 7, f = i & 127;
        s_w1T[f * KW1 + g] = f2bf(w1[i]);
    }
    for (int i = tid; i < (64 - GDIM) * 128; i += 256) {
        int g = GDIM + (i >> 7), f = i & 127;
        s_w1T[f * KW1 + g] = 0;
    }
    for (int i = tid; i < 128 * 128; i += 256) {
        int k = i >> 7, n = i & 127;
        s_w2T[n * KW2 + k] = f2bf(w2[i]);
    }

    const int lane = tid & 63;
    const int w    = tid >> 6;
    const int l15  = lane & 15;
    const int quad = lane >> 4;

    float b1v[8], b2v[8];
    #pragma unroll
    for (int nt = 0; nt < 8; nt++) {
        b1v[nt] = b1[nt * 16 + l15];
        b2v[nt] = b2[nt * 16 + l15];
    }
    __syncthreads();

    const float hstep = 6.0f / (float)(KTAB - 1);
    const float step  = 6.0f / 49.0f;
    const float coeff = -0.5f / (step * step);
    const float pioc  = 3.14159265358979323846f / 6.0f;
    const int k0 = bx * 64;
    const float dm = (float)(k0 + w * 16 + l15) * hstep;

    floatx4 acc1[8];
    #pragma unroll
    for (int nt = 0; nt < 8; nt++) acc1[nt] = (floatx4){0.f, 0.f, 0.f, 0.f};
    #pragma unroll
    for (int ks = 0; ks < 2; ks++) {
        unsigned int ap[4];
        #pragma unroll
        for (int jj = 0; jj < 4; jj++) {
            int g0 = ks * 32 + quad * 8 + 2 * jj;
            float d0 = dm - (float)g0 * step;
            float d1 = dm - (float)(g0 + 1) * step;
            float v0 = (g0 < GDIM)     ? __expf(coeff * d0 * d0) : 0.0f;
            float v1 = (g0 + 1 < GDIM) ? __expf(coeff * d1 * d1) : 0.0f;
            ap[jj] = pk2bf(v0, v1);
        }
        short8 af;
        __builtin_memcpy(&af, ap, 16);
        #pragma unroll
        for (int nt = 0; nt < 8; nt++) {
            short8 bfg = *(const short8*)&s_w1T[(nt * 16 + l15) * KW1 + ks * 32 + quad * 8];
            acc1[nt] = __builtin_amdgcn_mfma_f32_16x16x32_bf16(af, bfg, acc1[nt], 0, 0, 0);
        }
    }
    __syncthreads();   // all waves done reading s_w1T; s_t may alias it

    #pragma unroll
    for (int nt = 0; nt < 8; nt++) {
        #pragma unroll
        for (int r = 0; r < 4; r++) {
            int row = w * 16 + quad * 4 + r;
            s_t[row * KW2 + nt * 16 + l15] = f2bf(ssp(acc1[nt][r] + b1v[nt]));
        }
    }
    // no barrier: wave reads only rows it wrote

    floatx4 acc2[8];
    #pragma unroll
    for (int nt = 0; nt < 8; nt++) acc2[nt] = (floatx4){0.f, 0.f, 0.f, 0.f};
    #pragma unroll
    for (int ks = 0; ks < 4; ks++) {
        short8 af = *(const short8*)&s_t[(w * 16 + l15) * KW2 + ks * 32 + quad * 8];
        #pragma unroll
        for (int nt = 0; nt < 8; nt++) {
            short8 bfg = *(const short8*)&s_w2T[(nt * 16 + l15) * KW2 + ks * 32 + quad * 8];
            acc2[nt] = __builtin_amdgcn_mfma_f32_16x16x32_bf16(af, bfg, acc2[nt], 0, 0, 0);
        }
    }

    #pragma unroll
    for (int nt = 0; nt < 8; nt++) {
        #pragma unroll
        for (int r = 0; r < 4; r++) {
            int row = w * 16 + quad * 4 + r;
            float d = (float)(k0 + row) * hstep;
            float cut = 0.5f * (__cosf(d * pioc) + 1.0f);
            Tg[(size_t)(k0 + row) * 128 + nt * 16 + l15] = f2bf((acc2[nt][r] + b2v[nt]) * cut);
        }
    }
}

// ---------------------------------------------------------------------------
// Fully-fused SchNet: one block = one molecule, 512 threads = 8 waves.
// GEMM tile per wave: rows (w&1)*16, cols (w>>1)*32.
// Gather (R10 rewrite): DENSE 32x32 pair loop. Graph is ~87% dense (32 atoms,
// 6A cutoff in 10A box), so per-pair knot byte-offsets live in a flat
// s_ko[dst][src] LDS array; non-edges point at a zero table row (cutoff=0 at
// d>=6, so they contribute exactly 0 through the FMA). No rowptr, no slots,
// no degree imbalance, no branches. Per atom: 16 knot offsets prefetched via
// 4x ds_read_b128 broadcast, then a fully-unrolled 16-step loop with
// compile-time hx addresses -> 16-deep global-load pipelining.
// ---------------------------------------------------------------------------
__global__ __launch_bounds__(512, 4) void fused_schnet_kernel(
    const int* __restrict__ z, const float* __restrict__ emb,
    const int* __restrict__ rowptr, const unsigned int* __restrict__ meta,
    const unsigned short* __restrict__ Tt,
    const unsigned short* __restrict__ Wtall,
    const float* __restrict__ cf2_b, const float* __restrict__ lin_b,
    const float* __restrict__ out1_b, const float* __restrict__ out2_w,
    const float* __restrict__ out2_b,
    float* __restrict__ out)
{
    __shared__ float s_h[32 * STRH];                 // 16.9 KB fp32 node state
    __shared__ float s_hx[32 * 128];                 // 16.4 KB fp32
    __shared__ unsigned short s_agg[32 * STRA];      //  8.7 KB bf16
    __shared__ unsigned int s_ko[32 * 32];           //  4.0 KB pair knot offsets
    __shared__ float s_red;
    unsigned short* s_t = (unsigned short*)s_hx;     // [32][STRA] alias (8.7KB)

    const int tid  = threadIdx.x;
    const int lane = tid & 63;
    const int w    = tid >> 6;          // wave 0..7
    const int l15  = lane & 15;
    const int quad = lane >> 4;
    const int r16  = (w & 1) * 16;      // GEMM row tile
    const int c32  = (w >> 1) * 32;     // GEMM col tile
    const int B0   = blockIdx.x * 32;   // molecule base atom

    const int half = lane >> 5;         // gather: which pair of the step
    const int l31  = lane & 31;
    const unsigned tOff = (unsigned)(l31 << 3);   // 8B into table row (4 bf16)
    const unsigned hOff = (unsigned)(l31 << 4);   // 16B into hx row (4 f32)

    // init h; sentinel-fill pair table (zero-row offset)
    for (int i = tid; i < 32 * 128; i += 512) {
        int row = i >> 7, col = i & 127;
        s_h[row * STRH + col] = emb[(size_t)z[B0 + row] * 128 + col];
    }
    if (tid == 0) s_red = 0.0f;
    for (int i = tid; i < 32 * 32; i += 512)
        s_ko[i] = (unsigned)(KTAB << 8);             // sentinel: zero table row

    const int ebase = rowptr[B0];
    const int nE    = rowptr[B0 + 32] - ebase;

    __syncthreads();   // sentinel fill complete before edge overwrite

    // stage edges into dense pair table, split by src parity for half-wave
    // reads: s_ko[dst*32 + (src&1)*16 + src/2] = knot byte offset
    for (int i = tid; i < nE; i += 512) {
        unsigned q = meta[ebase + i];
        int dstA = q & 31, srcA = (q >> 5) & 31;
        s_ko[(dstA << 5) + ((srcA & 1) << 4) + (srcA >> 1)] = (q >> 10) << 8;
    }

    const unsigned short* WtO = Wtall + 9 * 16384;   // out1^T
    const char* hxB = (const char*)s_hx;

    for (int l = 0; l < 3; l++) {
        const unsigned short* W1 = Wtall + (size_t)(l * 3 + 0) * 16384;
        const unsigned short* W2 = Wtall + (size_t)(l * 3 + 1) * 16384;
        const unsigned short* W3 = Wtall + (size_t)(l * 3 + 2) * 16384;
        const char* TlB = (const char*)(Tt + (size_t)l * (KTAB + 1) * 128);

        __syncthreads();   // h ready (also covers init/s_ko staging at l=0)

        // ---- GEMM1: hx = h @ cf1 (16x32 tile per wave) ----
        floatx4 acc[2];
        #pragma unroll
        for (int nt = 0; nt < 2; nt++) acc[nt] = (floatx4){0.f, 0.f, 0.f, 0.f};
        #pragma unroll
        for (int ks = 0; ks < 4; ks++) {
            const float* hp = &s_h[(r16 + l15) * STRH + ks * 32 + quad * 8];
            float4 xa = *(const float4*)hp;
            float4 xb = *(const float4*)(hp + 4);
            unsigned int ap[4];
            ap[0] = pk2bf(xa.x, xa.y); ap[1] = pk2bf(xa.z, xa.w);
            ap[2] = pk2bf(xb.x, xb.y); ap[3] = pk2bf(xb.z, xb.w);
            short8 af;
            __builtin_memcpy(&af, ap, 16);
            #pragma unroll
            for (int nt = 0; nt < 2; nt++) {
                short8 bfg = *(const short8*)&W1[(size_t)(c32 + nt * 16 + l15) * 128 + ks * 32 + quad * 8];
                acc[nt] = __builtin_amdgcn_mfma_f32_16x16x32_bf16(af, bfg, acc[nt], 0, 0, 0);
            }
        }
        #pragma unroll
        for (int nt = 0; nt < 2; nt++) {
            #pragma unroll
            for (int r = 0; r < 4; r++)
                s_hx[(r16 + quad * 4 + r) * 128 + c32 + nt * 16 + l15] = acc[nt][r];
        }

        __syncthreads();   // hx complete before gather reads

        // ---- gather: dense pairs; wave per 4 atoms, 2 pairs/step, 4 ch/lane ----
        for (int al = 0; al < 4; al++) {
            const int atom = (w << 2) + al;
            const unsigned* ko = &s_ko[(atom << 5) + (half << 4)];
            uint4 k0 = *(const uint4*)&ko[0];
            uint4 k1 = *(const uint4*)&ko[4];
            uint4 k2 = *(const uint4*)&ko[8];
            uint4 k3 = *(const uint4*)&ko[12];
            const unsigned koff[16] = { k0.x, k0.y, k0.z, k0.w,
                                        k1.x, k1.y, k1.z, k1.w,
                                        k2.x, k2.y, k2.z, k2.w,
                                        k3.x, k3.y, k3.z, k3.w };
            float pa[4][4];
            #pragma unroll
            for (int j = 0; j < 4; j++) {
                #pragma unroll
                for (int c = 0; c < 4; c++) pa[j][c] = 0.0f;
            }
            #pragma unroll
            for (int stp = 0; stp < 16; stp++) {
                const int pr = (stp << 1) + half;        // src atom 0..31
                uint2 tp = *(const uint2*)(TlB + (koff[stp] + tOff));
                float4 hv = *(const float4*)(hxB + (unsigned)(pr << 9) + hOff);
                const int j = stp & 3;
                pa[j][0] = fmaf(hv.x, __uint_as_float(tp.x << 16),         pa[j][0]);
                pa[j][1] = fmaf(hv.y, __uint_as_float(tp.x & 0xffff0000u), pa[j][1]);
                pa[j][2] = fmaf(hv.z, __uint_as_float(tp.y << 16),         pa[j][2]);
                pa[j][3] = fmaf(hv.w, __uint_as_float(tp.y & 0xffff0000u), pa[j][3]);
            }
            float c0 = (pa[0][0] + pa[1][0]) + (pa[2][0] + pa[3][0]);
            float c1 = (pa[0][1] + pa[1][1]) + (pa[2][1] + pa[3][1]);
            float c2 = (pa[0][2] + pa[1][2]) + (pa[2][2] + pa[3][2]);
            float c3 = (pa[0][3] + pa[1][3]) + (pa[2][3] + pa[3][3]);
            c0 += __shfl_xor(c0, 32);
            c1 += __shfl_xor(c1, 32);
            c2 += __shfl_xor(c2, 32);
            c3 += __shfl_xor(c3, 32);
            if (half == 0) {
                uint2 pk = make_uint2(pk2bf(c0, c1), pk2bf(c2, c3));
                *(uint2*)&s_agg[atom * STRA + (l31 << 2)] = pk;
            }
        }

        __syncthreads();   // agg complete; hx reads done (s_t alias safe)

        // ---- GEMM2: t = ssp(agg @ cf2 + b) ----
        float bva[2], bvb[2];
        #pragma unroll
        for (int nt = 0; nt < 2; nt++) {
            bva[nt] = cf2_b[l * 128 + c32 + nt * 16 + l15];
            bvb[nt] = lin_b[l * 128 + c32 + nt * 16 + l15];
        }
        #pragma unroll
        for (int nt = 0; nt < 2; nt++) acc[nt] = (floatx4){0.f, 0.f, 0.f, 0.f};
        #pragma unroll
        for (int ks = 0; ks < 4; ks++) {
            short8 af = *(const short8*)&s_agg[(r16 + l15) * STRA + ks * 32 + quad * 8];
            #pragma unroll
            for (int nt = 0; nt < 2; nt++) {
                short8 bfg = *(const short8*)&W2[(size_t)(c32 + nt * 16 + l15) * 128 + ks * 32 + quad * 8];
                acc[nt] = __builtin_amdgcn_mfma_f32_16x16x32_bf16(af, bfg, acc[nt], 0, 0, 0);
            }
        }
        #pragma unroll
        for (int nt = 0; nt < 2; nt++) {
            #pragma unroll
            for (int r = 0; r < 4; r++) {
                int row = r16 + quad * 4 + r;
                s_t[row * STRA + c32 + nt * 16 + l15] = f2bf(ssp(acc[nt][r] + bva[nt]));
            }
        }

        __syncthreads();   // t complete (cross-wave cols needed by GEMM3)

        // ---- GEMM3: h += t @ lin + b ----
        #pragma unroll
        for (int nt = 0; nt < 2; nt++) acc[nt] = (floatx4){0.f, 0.f, 0.f, 0.f};
        #pragma unroll
        for (int ks = 0; ks < 4; ks++) {
            short8 af = *(const short8*)&s_t[(r16 + l15) * STRA + ks * 32 + quad * 8];
            #pragma unroll
            for (int nt = 0; nt < 2; nt++) {
                short8 bfg = *(const short8*)&W3[(size_t)(c32 + nt * 16 + l15) * 128 + ks * 32 + quad * 8];
                acc[nt] = __builtin_amdgcn_mfma_f32_16x16x32_bf16(af, bfg, acc[nt], 0, 0, 0);
            }
        }
        #pragma unroll
        for (int nt = 0; nt < 2; nt++) {
            #pragma unroll
            for (int r = 0; r < 4; r++) {
                int row = r16 + quad * 4 + r;
                s_h[row * STRH + c32 + nt * 16 + l15] += acc[nt][r] + bvb[nt];
            }
        }
        // loop-top __syncthreads covers h
    }

    __syncthreads();

    // ---- head: out = sum_a ssp(h@out1 + b1)@out2 + 32*b2 ----
    const int c16 = (w >> 1) * 16;   // out1: 64 cols = 4 col tiles x 2 row tiles
    floatx4 ha = (floatx4){0.f, 0.f, 0.f, 0.f};
    #pragma unroll
    for (int ks = 0; ks < 4; ks++) {
        const float* hp = &s_h[(r16 + l15) * STRH + ks * 32 + quad * 8];
        float4 xa = *(const float4*)hp;
        float4 xb = *(const float4*)(hp + 4);
        unsigned int ap[4];
        ap[0] = pk2bf(xa.x, xa.y); ap[1] = pk2bf(xa.z, xa.w);
        ap[2] = pk2bf(xb.x, xb.y); ap[3] = pk2bf(xb.z, xb.w);
        short8 af;
        __builtin_memcpy(&af, ap, 16);
        short8 bfg = *(const short8*)&WtO[(size_t)(c16 + l15) * 128 + ks * 32 + quad * 8];
        ha = __builtin_amdgcn_mfma_f32_16x16x32_bf16(af, bfg, ha, 0, 0, 0);
    }
    float part = 0.0f;
    {
        float b1o = out1_b[c16 + l15];
        float o2  = out2_w[c16 + l15];
        #pragma unroll
        for (int r = 0; r < 4; r++)
            part += ssp(ha[r] + b1o) * o2;
    }
    #pragma unroll
    for (int off = 32; off > 0; off >>= 1) part += __shfl_down(part, off);
    if (lane == 0) atomicAdd(&s_red, part);
    __syncthreads();
    if (tid == 0) out[blockIdx.x] = s_red + 32.0f * out2_b[0];
}

extern "C" void kernel_launch(void* const* d_in, const int* in_sizes, int n_in,
                              void* d_out, int out_size, void* d_ws, size_t ws_size,
                              hipStream_t stream)
{
    const int*   z      = (const int*)d_in[0];
    const float* pos    = (const float*)d_in[1];
    const int*   eidx   = (const int*)d_in[3];
    const float* emb    = (const float*)d_in[4];
    const float* mlp_w1 = (const float*)d_in[5];
    const float* mlp_b1 = (const float*)d_in[6];
    const float* mlp_w2 = (const float*)d_in[7];
    const float* mlp_b2 = (const float*)d_in[8];
    const float* cf1_w  = (const float*)d_in[9];
    const float* cf2_w  = (const float*)d_in[10];
    const float* cf2_b  = (const float*)d_in[11];
    const float* lin_w  = (const float*)d_in[12];
    const float* lin_b  = (const float*)d_in[13];
    const float* out1_w = (const float*)d_in[14];
    const float* out1_b = (const float*)d_in[15];
    const float* out2_w = (const float*)d_in[16];
    const float* out2_b = (const float*)d_in[17];
    const int E = in_sizes[3] / 2;

    // workspace carve-up (16B-aligned sections)
    char* p = (char*)d_ws;
    unsigned int* meta = (unsigned int*)p;        p += ((size_t)(E + 1) * 4 + 63) & ~63ULL;
    unsigned short* Tt = (unsigned short*)p;      p += (size_t)3 * (KTAB + 1) * 128 * 2;
    int* rowptr = (int*)p;                        p += ((size_t)(NATOMS + 1) * 4 + 63) & ~63ULL;
    unsigned short* Wtall = (unsigned short*)p;   // 9*16384 + 64*128 ushorts

    const int EB = (E + NATOMS + 1 + 3 * 128 + 255) / 256;
    const int WB = (9 * 16384 + 64 * 128 + 255) / 256;
    const int TB = NTILE * 3;
    mega_setup_kernel<<<EB + WB + TB, 256, 0, stream>>>(
        pos, eidx, E, EB, rowptr, cf1_w, cf2_w, lin_w, out1_w, Wtall, meta,
        mlp_w1, mlp_b1, mlp_w2, mlp_b2, Tt);

    fused_schnet_kernel<<<NMOL, 512, 0, stream>>>(
        z, emb, rowptr, meta, Tt, Wtall,
        cf2_b, lin_b, out1_b, out2_w, out2_b, (float*)d_out);
}

// Round 3
// 161.213 us; speedup vs baseline: 1.1054x; 1.0542x over previous
//
#include <hip/hip_runtime.h>
#include <hip/hip_bf16.h>
#include <math.h>

// Problem constants (SchNet reference)
#define NATOMS 16384
#define NMOL   512
#define APM    32
#define GDIM   50
#define KTAB   4096   // filter lookup-table knots over d in [0,6] (nearest-knot)

#define STRH 132      // s_h row stride (floats), 528B
#define STRA 136      // s_agg / s_t row stride (ushorts), 272B

typedef __attribute__((ext_vector_type(8))) short   short8;   // 8 bf16 (A/B frag)
typedef __attribute__((ext_vector_type(4))) float   floatx4;  // C/D frag

// fast shifted softplus: log(1+exp(x)) - log2, via HW v_exp_f32/v_log_f32
__device__ __forceinline__ float ssp(float x) {
    float e = __expf(-fabsf(x));
    return fmaxf(x, 0.0f) + __logf(1.0f + e) - 0.69314718055994531f;
}

__device__ __forceinline__ unsigned short f2bf(float x) {
    union { float f; unsigned int u; } v; v.f = x;
    unsigned int lsb = (v.u >> 16) & 1u;
    v.u += 0x7fffu + lsb;
    return (unsigned short)(v.u >> 16);
}

__device__ __forceinline__ unsigned int pk2bf(float a, float b) {
    __hip_bfloat162 h = __float22bfloat162_rn(make_float2(a, b));
    unsigned int u;
    __builtin_memcpy(&u, &h, 4);
    return u;
}

// ---------------------------------------------------------------------------
// MEGA-SETUP (single dispatch, 3 block regions):
//  [0,EB):        per-edge meta {knot<<10 | src<<5 | dst} + rowptr + zero-rows
//  [EB,EB+WB):    weights fp32 -> bf16 B-frag transpose (9x128x128 + out1 64x128)
//  [EB+WB, +192): filter table, 64 tiles x 3 layers, plain bf16 rows:
//                 T[l][k][f] = ((ssp(ea(d_k)@w1+b1)@w2)+b2)*cut(d_k)
//  Each layer gets KTAB+1 rows; row KTAB is all-zero (dense-gather sentinel).
// ---------------------------------------------------------------------------
#define KW1 72
#define KW2 136
#define NTILE (KTAB / 64)   // 64 tiles per layer

__global__ __launch_bounds__(256) void mega_setup_kernel(
    const float* __restrict__ pos, const int* __restrict__ eidx, int E, int EB,
    int* __restrict__ rowptr,
    const float* __restrict__ cf1, const float* __restrict__ cf2,
    const float* __restrict__ lin, const float* __restrict__ out1,
    unsigned short* __restrict__ Wtall, unsigned int* __restrict__ meta,
    const float* __restrict__ w1_, const float* __restrict__ b1_,
    const float* __restrict__ w2_, const float* __restrict__ b2_,
    unsigned short* __restrict__ Tt)
{
    const int WB = (9 * 16384 + 64 * 128 + 255) / 256;
    const int b = blockIdx.x;
    const int tid = threadIdx.x;

    if (b < EB) {
        int idx = b * 256 + tid;
        if (idx < E) {
            int s = eidx[idx], t = eidx[E + idx];
            float dx = pos[3 * s]     - pos[3 * t];
            float dy = pos[3 * s + 1] - pos[3 * t + 1];
            float dz = pos[3 * s + 2] - pos[3 * t + 2];
            float d  = sqrtf(dx * dx + dy * dy + dz * dz);
            float u  = d * (float)(KTAB - 1) / 6.0f;
            int i = min((int)(u + 0.5f), KTAB - 1);   // nearest knot
            meta[idx] = ((unsigned)i << 10) | ((unsigned)(s & 31) << 5) | (unsigned)(t & 31);
        } else if (idx < E + NATOMS + 1) {
            int a = idx - E;
            int lo = 0, hi = E;
            while (lo < hi) { int mid = (lo + hi) >> 1; if (eidx[mid] < a) lo = mid + 1; else hi = mid; }
            rowptr[a] = lo;
        } else if (idx < E + NATOMS + 1 + 3 * 128) {
            int q = idx - (E + NATOMS + 1);
            int l = q >> 7, f = q & 127;
            Tt[(size_t)l * (KTAB + 1) * 128 + (size_t)KTAB * 128 + f] = 0;  // zero row
        }
        return;
    }
    if (b < EB + WB) {
        int idx = (b - EB) * 256 + tid;
        if (idx < 9 * 16384) {
            int wi = idx >> 14, rem = idx & 16383;
            int n = rem >> 7, k = rem & 127;
            int l = wi / 3, which = wi % 3;
            const float* src = (which == 0) ? cf1 : (which == 1) ? cf2 : lin;
            Wtall[idx] = f2bf(src[(size_t)l * 16384 + k * 128 + n]);
        } else if (idx < 9 * 16384 + 64 * 128) {
            int q = idx - 9 * 16384;
            int n = q >> 7, k = q & 127;
            Wtall[idx] = f2bf(out1[k * 64 + n]);
        }
        return;
    }

    // ---------------- table region: tt = (layer, tile) ----------------
    __shared__ unsigned short s_bufA[128 * KW2];   // w2T
    __shared__ unsigned short s_bufB[128 * KW1];   // w1T, then s_t (alias)

    const int tt = b - EB - WB;
    const int l  = tt / NTILE;
    const int bx = tt % NTILE;
    const float* w1 = w1_ + (size_t)l * GDIM * 128;
    const float* b1 = b1_ + (size_t)l * 128;
    const float* w2 = w2_ + (size_t)l * 128 * 128;
    const float* b2 = b2_ + (size_t)l * 128;
    unsigned short* Tg = Tt + (size_t)l * (KTAB + 1) * 128;

    unsigned short* s_w1T = s_bufB;                // [128][KW1]
    unsigned short* s_w2T = s_bufA;                // [128][KW2]
    unsigned short* s_t   = s_bufB;                // [64][KW2] (after barrier)

    for (int i = tid; i < GDIM * 128; i += 256) {
        int g = i >> 7, f = i & 127;
        s_w1T[f * KW1 + g] = f2bf(w1[i]);
    }
    for (int i = tid; i < (64 - GDIM) * 128; i += 256) {
        int g = GDIM + (i >> 7), f = i & 127;
        s_w1T[f * KW1 + g] = 0;
    }
    for (int i = tid; i < 128 * 128; i += 256) {
        int k = i >> 7, n = i & 127;
        s_w2T[n * KW2 + k] = f2bf(w2[i]);
    }

    const int lane = tid & 63;
    const int w    = tid >> 6;
    const int l15  = lane & 15;
    const int quad = lane >> 4;

    float b1v[8], b2v[8];
    #pragma unroll
    for (int nt = 0; nt < 8; nt++) {
        b1v[nt] = b1[nt * 16 + l15];
        b2v[nt] = b2[nt * 16 + l15];
    }
    __syncthreads();

    const float hstep = 6.0f / (float)(KTAB - 1);
    const float step  = 6.0f / 49.0f;
    const float coeff = -0.5f / (step * step);
    const float pioc  = 3.14159265358979323846f / 6.0f;
    const int k0 = bx * 64;
    const float dm = (float)(k0 + w * 16 + l15) * hstep;

    floatx4 acc1[8];
    #pragma unroll
    for (int nt = 0; nt < 8; nt++) acc1[nt] = (floatx4){0.f, 0.f, 0.f, 0.f};
    #pragma unroll
    for (int ks = 0; ks < 2; ks++) {
        unsigned int ap[4];
        #pragma unroll
        for (int jj = 0; jj < 4; jj++) {
            int g0 = ks * 32 + quad * 8 + 2 * jj;
            float d0 = dm - (float)g0 * step;
            float d1 = dm - (float)(g0 + 1) * step;
            float v0 = (g0 < GDIM)     ? __expf(coeff * d0 * d0) : 0.0f;
            float v1 = (g0 + 1 < GDIM) ? __expf(coeff * d1 * d1) : 0.0f;
            ap[jj] = pk2bf(v0, v1);
        }
        short8 af;
        __builtin_memcpy(&af, ap, 16);
        #pragma unroll
        for (int nt = 0; nt < 8; nt++) {
            short8 bfg = *(const short8*)&s_w1T[(nt * 16 + l15) * KW1 + ks * 32 + quad * 8];
            acc1[nt] = __builtin_amdgcn_mfma_f32_16x16x32_bf16(af, bfg, acc1[nt], 0, 0, 0);
        }
    }
    __syncthreads();   // all waves done reading s_w1T; s_t may alias it

    #pragma unroll
    for (int nt = 0; nt < 8; nt++) {
        #pragma unroll
        for (int r = 0; r < 4; r++) {
            int row = w * 16 + quad * 4 + r;
            s_t[row * KW2 + nt * 16 + l15] = f2bf(ssp(acc1[nt][r] + b1v[nt]));
        }
    }
    // no barrier: wave reads only rows it wrote

    floatx4 acc2[8];
    #pragma unroll
    for (int nt = 0; nt < 8; nt++) acc2[nt] = (floatx4){0.f, 0.f, 0.f, 0.f};
    #pragma unroll
    for (int ks = 0; ks < 4; ks++) {
        short8 af = *(const short8*)&s_t[(w * 16 + l15) * KW2 + ks * 32 + quad * 8];
        #pragma unroll
        for (int nt = 0; nt < 8; nt++) {
            short8 bfg = *(const short8*)&s_w2T[(nt * 16 + l15) * KW2 + ks * 32 + quad * 8];
            acc2[nt] = __builtin_amdgcn_mfma_f32_16x16x32_bf16(af, bfg, acc2[nt], 0, 0, 0);
        }
    }

    #pragma unroll
    for (int nt = 0; nt < 8; nt++) {
        #pragma unroll
        for (int r = 0; r < 4; r++) {
            int row = w * 16 + quad * 4 + r;
            float d = (float)(k0 + row) * hstep;
            float cut = 0.5f * (__cosf(d * pioc) + 1.0f);
            Tg[(size_t)(k0 + row) * 128 + nt * 16 + l15] = f2bf((acc2[nt][r] + b2v[nt]) * cut);
        }
    }
}

// ---------------------------------------------------------------------------
// Fully-fused SchNet: one block = one molecule, 512 threads = 8 waves.
// GEMM tile per wave: rows (w&1)*16, cols (w>>1)*32.
// Gather (R11 rewrite): CHANNEL-PARALLEL dense pair loop. Wave owns 4 dst
// atoms; lane = 2 channels spanning the full 128-ch row. Per src step:
// ONE ds_read_b64 of hx[s] shared by all 4 dst (8x less LDS than R10's
// per-dst b128), 4 coalesced dword loads of table rows (knot offsets are
// wave-uniform -> hoisted to SGPR via readfirstlane, saddr+voffset, zero
// VALU addr math), 4x(2 unpack + 2 FMA). No shuffles, no combine: lanes
// own their output channels; non-edges hit the zero table row.
// ---------------------------------------------------------------------------
__global__ __launch_bounds__(512, 4) void fused_schnet_kernel(
    const int* __restrict__ z, const float* __restrict__ emb,
    const int* __restrict__ rowptr, const unsigned int* __restrict__ meta,
    const unsigned short* __restrict__ Tt,
    const unsigned short* __restrict__ Wtall,
    const float* __restrict__ cf2_b, const float* __restrict__ lin_b,
    const float* __restrict__ out1_b, const float* __restrict__ out2_w,
    const float* __restrict__ out2_b,
    float* __restrict__ out)
{
    __shared__ float s_h[32 * STRH];                 // 16.9 KB fp32 node state
    __shared__ float s_hx[32 * 128];                 // 16.4 KB fp32
    __shared__ unsigned short s_agg[32 * STRA];      //  8.7 KB bf16
    __shared__ unsigned int s_ko[32 * 32];           //  4.0 KB pair knot offsets
    __shared__ float s_red;
    unsigned short* s_t = (unsigned short*)s_hx;     // [32][STRA] alias (8.7KB)

    const int tid  = threadIdx.x;
    const int lane = tid & 63;
    const int w    = tid >> 6;          // wave 0..7
    const int l15  = lane & 15;
    const int quad = lane >> 4;
    const int r16  = (w & 1) * 16;      // GEMM row tile
    const int c32  = (w >> 1) * 32;     // GEMM col tile
    const int B0   = blockIdx.x * 32;   // molecule base atom

    // init h; sentinel-fill pair table (zero-row offset)
    for (int i = tid; i < 32 * 128; i += 512) {
        int row = i >> 7, col = i & 127;
        s_h[row * STRH + col] = emb[(size_t)z[B0 + row] * 128 + col];
    }
    if (tid == 0) s_red = 0.0f;
    for (int i = tid; i < 32 * 32; i += 512)
        s_ko[i] = (unsigned)(KTAB << 8);             // sentinel: zero table row

    const int ebase = rowptr[B0];
    const int nE    = rowptr[B0 + 32] - ebase;

    __syncthreads();   // sentinel fill complete before edge overwrite

    // stage edges into dense pair table: s_ko[dst*32 + src] = knot byte offset
    for (int i = tid; i < nE; i += 512) {
        unsigned q = meta[ebase + i];
        int dstA = q & 31, srcA = (q >> 5) & 31;
        s_ko[(dstA << 5) + srcA] = (q >> 10) << 8;
    }

    const unsigned short* WtO = Wtall + 9 * 16384;   // out1^T

    for (int l = 0; l < 3; l++) {
        const unsigned short* W1 = Wtall + (size_t)(l * 3 + 0) * 16384;
        const unsigned short* W2 = Wtall + (size_t)(l * 3 + 1) * 16384;
        const unsigned short* W3 = Wtall + (size_t)(l * 3 + 2) * 16384;
        const char* TlB = (const char*)(Tt + (size_t)l * (KTAB + 1) * 128);

        __syncthreads();   // h ready (also covers init/s_ko staging at l=0)

        // ---- GEMM1: hx = h @ cf1 (16x32 tile per wave) ----
        floatx4 acc[2];
        #pragma unroll
        for (int nt = 0; nt < 2; nt++) acc[nt] = (floatx4){0.f, 0.f, 0.f, 0.f};
        #pragma unroll
        for (int ks = 0; ks < 4; ks++) {
            const float* hp = &s_h[(r16 + l15) * STRH + ks * 32 + quad * 8];
            float4 xa = *(const float4*)hp;
            float4 xb = *(const float4*)(hp + 4);
            unsigned int ap[4];
            ap[0] = pk2bf(xa.x, xa.y); ap[1] = pk2bf(xa.z, xa.w);
            ap[2] = pk2bf(xb.x, xb.y); ap[3] = pk2bf(xb.z, xb.w);
            short8 af;
            __builtin_memcpy(&af, ap, 16);
            #pragma unroll
            for (int nt = 0; nt < 2; nt++) {
                short8 bfg = *(const short8*)&W1[(size_t)(c32 + nt * 16 + l15) * 128 + ks * 32 + quad * 8];
                acc[nt] = __builtin_amdgcn_mfma_f32_16x16x32_bf16(af, bfg, acc[nt], 0, 0, 0);
            }
        }
        #pragma unroll
        for (int nt = 0; nt < 2; nt++) {
            #pragma unroll
            for (int r = 0; r < 4; r++)
                s_hx[(r16 + quad * 4 + r) * 128 + c32 + nt * 16 + l15] = acc[nt][r];
        }

        __syncthreads();   // hx complete before gather reads

        // ---- gather: channel-parallel; wave owns 4 dst, lane = 2 channels ----
        {
            float acc0[4], acc1[4];
            #pragma unroll
            for (int i = 0; i < 4; i++) { acc0[i] = 0.0f; acc1[i] = 0.0f; }
            #pragma unroll
            for (int sc = 0; sc < 4; sc++) {
                // wave-uniform knot byte-offsets -> SGPRs (broadcast LDS reads)
                unsigned ko[4][8];
                #pragma unroll
                for (int i = 0; i < 4; i++) {
                    uint4 ka = *(const uint4*)&s_ko[(((w << 2) + i) << 5) + (sc << 3)];
                    uint4 kb = *(const uint4*)&s_ko[(((w << 2) + i) << 5) + (sc << 3) + 4];
                    ko[i][0] = __builtin_amdgcn_readfirstlane(ka.x);
                    ko[i][1] = __builtin_amdgcn_readfirstlane(ka.y);
                    ko[i][2] = __builtin_amdgcn_readfirstlane(ka.z);
                    ko[i][3] = __builtin_amdgcn_readfirstlane(ka.w);
                    ko[i][4] = __builtin_amdgcn_readfirstlane(kb.x);
                    ko[i][5] = __builtin_amdgcn_readfirstlane(kb.y);
                    ko[i][6] = __builtin_amdgcn_readfirstlane(kb.z);
                    ko[i][7] = __builtin_amdgcn_readfirstlane(kb.w);
                }
                #pragma unroll
                for (int j = 0; j < 8; j++) {
                    float2 hv = *(const float2*)&s_hx[(((sc << 3) + j) << 7) + (lane << 1)];
                    #pragma unroll
                    for (int i = 0; i < 4; i++) {
                        unsigned tp = *(const unsigned*)(TlB + ko[i][j] + (unsigned)(lane << 2));
                        acc0[i] = fmaf(hv.x, __uint_as_float(tp << 16),         acc0[i]);
                        acc1[i] = fmaf(hv.y, __uint_as_float(tp & 0xffff0000u), acc1[i]);
                    }
                }
            }
            #pragma unroll
            for (int i = 0; i < 4; i++)
                *(unsigned*)&s_agg[(((w << 2) + i)) * STRA + (lane << 1)] = pk2bf(acc0[i], acc1[i]);
        }

        __syncthreads();   // agg complete; hx reads done (s_t alias safe)

        // ---- GEMM2: t = ssp(agg @ cf2 + b) ----
        float bva[2], bvb[2];
        #pragma unroll
        for (int nt = 0; nt < 2; nt++) {
            bva[nt] = cf2_b[l * 128 + c32 + nt * 16 + l15];
            bvb[nt] = lin_b[l * 128 + c32 + nt * 16 + l15];
        }
        #pragma unroll
        for (int nt = 0; nt < 2; nt++) acc[nt] = (floatx4){0.f, 0.f, 0.f, 0.f};
        #pragma unroll
        for (int ks = 0; ks < 4; ks++) {
            short8 af = *(const short8*)&s_agg[(r16 + l15) * STRA + ks * 32 + quad * 8];
            #pragma unroll
            for (int nt = 0; nt < 2; nt++) {
                short8 bfg = *(const short8*)&W2[(size_t)(c32 + nt * 16 + l15) * 128 + ks * 32 + quad * 8];
                acc[nt] = __builtin_amdgcn_mfma_f32_16x16x32_bf16(af, bfg, acc[nt], 0, 0, 0);
            }
        }
        #pragma unroll
        for (int nt = 0; nt < 2; nt++) {
            #pragma unroll
            for (int r = 0; r < 4; r++) {
                int row = r16 + quad * 4 + r;
                s_t[row * STRA + c32 + nt * 16 + l15] = f2bf(ssp(acc[nt][r] + bva[nt]));
            }
        }

        __syncthreads();   // t complete (cross-wave cols needed by GEMM3)

        // ---- GEMM3: h += t @ lin + b ----
        #pragma unroll
        for (int nt = 0; nt < 2; nt++) acc[nt] = (floatx4){0.f, 0.f, 0.f, 0.f};
        #pragma unroll
        for (int ks = 0; ks < 4; ks++) {
            short8 af = *(const short8*)&s_t[(r16 + l15) * STRA + ks * 32 + quad * 8];
            #pragma unroll
            for (int nt = 0; nt < 2; nt++) {
                short8 bfg = *(const short8*)&W3[(size_t)(c32 + nt * 16 + l15) * 128 + ks * 32 + quad * 8];
                acc[nt] = __builtin_amdgcn_mfma_f32_16x16x32_bf16(af, bfg, acc[nt], 0, 0, 0);
            }
        }
        #pragma unroll
        for (int nt = 0; nt < 2; nt++) {
            #pragma unroll
            for (int r = 0; r < 4; r++) {
                int row = r16 + quad * 4 + r;
                s_h[row * STRH + c32 + nt * 16 + l15] += acc[nt][r] + bvb[nt];
            }
        }
        // loop-top __syncthreads covers h
    }

    __syncthreads();

    // ---- head: out = sum_a ssp(h@out1 + b1)@out2 + 32*b2 ----
    const int c16 = (w >> 1) * 16;   // out1: 64 cols = 4 col tiles x 2 row tiles
    floatx4 ha = (floatx4){0.f, 0.f, 0.f, 0.f};
    #pragma unroll
    for (int ks = 0; ks < 4; ks++) {
        const float* hp = &s_h[(r16 + l15) * STRH + ks * 32 + quad * 8];
        float4 xa = *(const float4*)hp;
        float4 xb = *(const float4*)(hp + 4);
        unsigned int ap[4];
        ap[0] = pk2bf(xa.x, xa.y); ap[1] = pk2bf(xa.z, xa.w);
        ap[2] = pk2bf(xb.x, xb.y); ap[3] = pk2bf(xb.z, xb.w);
        short8 af;
        __builtin_memcpy(&af, ap, 16);
        short8 bfg = *(const short8*)&WtO[(size_t)(c16 + l15) * 128 + ks * 32 + quad * 8];
        ha = __builtin_amdgcn_mfma_f32_16x16x32_bf16(af, bfg, ha, 0, 0, 0);
    }
    float part = 0.0f;
    {
        float b1o = out1_b[c16 + l15];
        float o2  = out2_w[c16 + l15];
        #pragma unroll
        for (int r = 0; r < 4; r++)
            part += ssp(ha[r] + b1o) * o2;
    }
    #pragma unroll
    for (int off = 32; off > 0; off >>= 1) part += __shfl_down(part, off);
    if (lane == 0) atomicAdd(&s_red, part);
    __syncthreads();
    if (tid == 0) out[blockIdx.x] = s_red + 32.0f * out2_b[0];
}

extern "C" void kernel_launch(void* const* d_in, const int* in_sizes, int n_in,
                              void* d_out, int out_size, void* d_ws, size_t ws_size,
                              hipStream_t stream)
{
    const int*   z      = (const int*)d_in[0];
    const float* pos    = (const float*)d_in[1];
    const int*   eidx   = (const int*)d_in[3];
    const float* emb    = (const float*)d_in[4];
    const float* mlp_w1 = (const float*)d_in[5];
    const float* mlp_b1 = (const float*)d_in[6];
    const float* mlp_w2 = (const float*)d_in[7];
    const float* mlp_b2 = (const float*)d_in[8];
    const float* cf1_w  = (const float*)d_in[9];
    const float* cf2_w  = (const float*)d_in[10];
    const float* cf2_b  = (const float*)d_in[11];
    const float* lin_w  = (const float*)d_in[12];
    const float* lin_b  = (const float*)d_in[13];
    const float* out1_w = (const float*)d_in[14];
    const float* out1_b = (const float*)d_in[15];
    const float* out2_w = (const float*)d_in[16];
    const float* out2_b = (const float*)d_in[17];
    const int E = in_sizes[3] / 2;

    // workspace carve-up (16B-aligned sections)
    char* p = (char*)d_ws;
    unsigned int* meta = (unsigned int*)p;        p += ((size_t)(E + 1) * 4 + 63) & ~63ULL;
    unsigned short* Tt = (unsigned short*)p;      p += (size_t)3 * (KTAB + 1) * 128 * 2;
    int* rowptr = (int*)p;                        p += ((size_t)(NATOMS + 1) * 4 + 63) & ~63ULL;
    unsigned short* Wtall = (unsigned short*)p;   // 9*16384 + 64*128 ushorts

    const int EB = (E + NATOMS + 1 + 3 * 128 + 255) / 256;
    const int WB = (9 * 16384 + 64 * 128 + 255) / 256;
    const int TB = NTILE * 3;
    mega_setup_kernel<<<EB + WB + TB, 256, 0, stream>>>(
        pos, eidx, E, EB, rowptr, cf1_w, cf2_w, lin_w, out1_w, Wtall, meta,
        mlp_w1, mlp_b1, mlp_w2, mlp_b2, Tt);

    fused_schnet_kernel<<<NMOL, 512, 0, stream>>>(
        z, emb, rowptr, meta, Tt, Wtall,
        cf2_b, lin_b, out1_b, out2_w, out2_b, (float*)d_out);
}